// Round 7
// baseline (84.687 us; speedup 1.0000x reference)
//
#include <hip/hip_runtime.h>
#include <hip/hip_bf16.h>
#include <stdint.h>

// Problem constants
#define S_LEN   4096
#define HIDDEN  1024
#define NHEAD   16
#define NKV     4
#define HD      64
#define WINDOW  512
#define L2E     1.4426950408889634f
#define QSCALE  (0.125f * L2E)

using short8 = __attribute__((ext_vector_type(8))) short;
using f32x4  = __attribute__((ext_vector_type(4))) float;
using f32x16 = __attribute__((ext_vector_type(16))) float;

// fp32 -> bf16, round-to-nearest-even
__device__ __forceinline__ uint16_t f2bf(float f) {
  uint32_t u = __builtin_bit_cast(uint32_t, f);
  u += 0x7fffu + ((u >> 16) & 1u);
  return (uint16_t)(u >> 16);
}
// round-to-nearest (ties up) — P values only (all >=0, bias ~2^-17)
__device__ __forceinline__ uint16_t f2bf_rn(float f) {
  uint32_t u = __builtin_bit_cast(uint32_t, f);
  return (uint16_t)((u + 0x8000u) >> 16);
}
__device__ __forceinline__ uint32_t pk2(float a, float b) {
  return (uint32_t)f2bf_rn(a) | ((uint32_t)f2bf_rn(b) << 16);
}

// async global->LDS, 16B per lane. LDS dest must be wave-uniform base + lane*16.
__device__ __forceinline__ void gld_lds16(void* lds, const void* g) {
  __builtin_amdgcn_global_load_lds(
      (const __attribute__((address_space(1))) char*)g,
      (__attribute__((address_space(3))) char*)lds, 16, 0, 0);
}

// ---------------------------------------------------------------------------
// Kernel 1: pack x, wq|wk|wv (concat rows), wo to bf16
// ---------------------------------------------------------------------------
__global__ __launch_bounds__(256) void k_tobf16(
    const float* __restrict__ x, const float* __restrict__ wq,
    const float* __restrict__ wk, const float* __restrict__ wv,
    const float* __restrict__ wo,
    uint16_t* __restrict__ xb, uint16_t* __restrict__ wqkvb,
    uint16_t* __restrict__ wob) {
  int i = blockIdx.x * 256 + threadIdx.x;  // one float4 per thread, exact grid
  const float4* src; uint16_t* dst; int off;
  if (i < 1048576)      { src = (const float4*)x;  dst = xb;                off = i; }
  else if (i < 1310720) { src = (const float4*)wq; dst = wqkvb;             off = i - 1048576; }
  else if (i < 1376256) { src = (const float4*)wk; dst = wqkvb + 1024*1024; off = i - 1310720; }
  else if (i < 1441792) { src = (const float4*)wv; dst = wqkvb + 1280*1024; off = i - 1376256; }
  else                  { src = (const float4*)wo; dst = wob;               off = i - 1441792; }
  float4 v = src[off];
  ushort4 o = { f2bf(v.x), f2bf(v.y), f2bf(v.z), f2bf(v.w) };
  *(ushort4*)(dst + (size_t)off * 4) = o;
}

// ---------------------------------------------------------------------------
// Kernel 2: QKV GEMM with fused RMSNorm + RoPE + cast + layout epilogue.
// BM=64, BN=128, BK=64; 4 waves in 2x2, wave tile 32x64 (acc[2][4]).
// Grid (64, 12) = 768 blocks = exactly 3 blocks/CU.
// ---------------------------------------------------------------------------
__global__ __launch_bounds__(256) void k_gemm_qkv(
    const uint16_t* __restrict__ A, const uint16_t* __restrict__ B,
    const float* __restrict__ cosb, const float* __restrict__ sinb,
    const float* __restrict__ qw, const float* __restrict__ kw,
    uint16_t* __restrict__ qout, uint16_t* __restrict__ kout,
    uint16_t* __restrict__ vtout) {
  __shared__ uint16_t As[64 * 64];
  __shared__ uint16_t Bs[128 * 64];
  const int K = 1024;
  const int t = threadIdx.x;
  const int lane = t & 63, w = t >> 6;
  const int wr = w >> 1, wc = w & 1;
  const int l16 = lane & 15, lg = lane >> 4;
  const int bm = blockIdx.x, bn = blockIdx.y;
  const uint16_t* Ab = A + (size_t)bm * 64 * K;
  const uint16_t* Bb = B + (size_t)bn * 128 * K;
  f32x4 acc[2][4] = {};
  for (int k0 = 0; k0 < K; k0 += 64) {
    __syncthreads();
    {  // stage A: 64x64 = 512 16B-chunks -> 2/thread
      int row = t >> 3, c8 = (t & 7) << 3;
      gld_lds16(&As[t * 8], Ab + (size_t)row * K + k0 + c8);
      int t2 = t + 256, row2 = t2 >> 3, c82 = (t2 & 7) << 3;
      gld_lds16(&As[t2 * 8], Ab + (size_t)row2 * K + k0 + c82);
    }
#pragma unroll
    for (int it = 0; it < 4; ++it) {  // stage B: 128x64 -> 4/thread
      int idx = it * 256 + t;
      int row = idx >> 3, c8 = (idx & 7) << 3;
      gld_lds16(&Bs[idx * 8], Bb + (size_t)row * K + k0 + c8);
    }
    __syncthreads();
#pragma unroll
    for (int kk = 0; kk < 2; ++kk) {
      short8 af[2], bq[4];
#pragma unroll
      for (int i = 0; i < 2; ++i)
        af[i] = *(const short8*)&As[(wr * 32 + i * 16 + l16) * 64 + kk * 32 + lg * 8];
#pragma unroll
      for (int j = 0; j < 4; ++j)
        bq[j] = *(const short8*)&Bs[(wc * 64 + j * 16 + l16) * 64 + kk * 32 + lg * 8];
#pragma unroll
      for (int i = 0; i < 2; ++i)
#pragma unroll
        for (int j = 0; j < 4; ++j)
          acc[i][j] = __builtin_amdgcn_mfma_f32_16x16x32_bf16(af[i], bq[j], acc[i][j], 0, 0, 0);
    }
  }

  // ---- fused epilogue ----
  const int hg = bn * 2 + wc;   // global 64-wide head slot, uniform per wave
  if (hg >= 20) {               // V: cast + transposed store
    const int kvh = hg - 20;
#pragma unroll
    for (int i = 0; i < 2; ++i) {
      int row0 = bm * 64 + wr * 32 + i * 16 + lg * 4;
#pragma unroll
      for (int j = 0; j < 4; ++j) {
        int d = j * 16 + l16;
        ushort4 o = { f2bf(acc[i][j][0]), f2bf(acc[i][j][1]),
                      f2bf(acc[i][j][2]), f2bf(acc[i][j][3]) };
        *(ushort4*)(vtout + (size_t)(kvh * 64 + d) * S_LEN + row0) = o;
      }
    }
    return;
  }
  // Q/K: RMSNorm + RoPE
  const float* nw = (hg < 16) ? qw : kw;
  float wgt[4];
#pragma unroll
  for (int j = 0; j < 4; ++j) wgt[j] = nw[j * 16 + l16];
#pragma unroll
  for (int i = 0; i < 2; ++i) {
    int row0 = bm * 64 + wr * 32 + i * 16 + lg * 4;
    float qn[4][4];
#pragma unroll
    for (int r = 0; r < 4; ++r) {
      float ss = acc[i][0][r] * acc[i][0][r] + acc[i][1][r] * acc[i][1][r]
               + acc[i][2][r] * acc[i][2][r] + acc[i][3][r] * acc[i][3][r];
      ss += __shfl_xor(ss, 1);
      ss += __shfl_xor(ss, 2);
      ss += __shfl_xor(ss, 4);
      ss += __shfl_xor(ss, 8);
      float inv = rsqrtf(ss * (1.0f / 64.0f) + 1e-5f);
#pragma unroll
      for (int j = 0; j < 4; ++j) qn[j][r] = acc[i][j][r] * inv * wgt[j];
    }
#pragma unroll
    for (int j = 0; j < 4; ++j) {
      int d = j * 16 + l16;
#pragma unroll
      for (int r = 0; r < 4; ++r) {
        int row = row0 + r;
        float rot = (j < 2) ? -qn[j + 2][r] : qn[j - 2][r];   // rotate_half
        float o = qn[j][r] * cosb[row * 64 + d] + rot * sinb[row * 64 + d];
        if (hg < 16)
          qout[(size_t)row * HIDDEN + hg * 64 + d] = f2bf(o * QSCALE);
        else
          kout[((size_t)(hg - 16) * S_LEN + row) * 64 + d] = f2bf(o);
      }
    }
  }
}

// ---------------------------------------------------------------------------
// Kernel 4: C[M][N] = A[M][K] * B[N][K]^T — output projection.
// ---------------------------------------------------------------------------
__global__ __launch_bounds__(256) void k_gemm_bf16(
    const uint16_t* __restrict__ A, const uint16_t* __restrict__ B,
    float* __restrict__ C, int N, int K) {
  __shared__ uint16_t As[64 * 64];
  __shared__ uint16_t Bs[128 * 64];
  const int t = threadIdx.x;
  const int lane = t & 63, w = t >> 6;
  const int wr = w >> 1, wc = w & 1;
  const int l16 = lane & 15, lg = lane >> 4;
  const int bm = blockIdx.x, bn = blockIdx.y;
  const uint16_t* Ab = A + (size_t)bm * 64 * K;
  const uint16_t* Bb = B + (size_t)bn * 128 * K;
  f32x4 acc[2][4] = {};
  for (int k0 = 0; k0 < K; k0 += 64) {
    __syncthreads();
    {
      int row = t >> 3, c8 = (t & 7) << 3;
      gld_lds16(&As[t * 8], Ab + (size_t)row * K + k0 + c8);
      int t2 = t + 256, row2 = t2 >> 3, c82 = (t2 & 7) << 3;
      gld_lds16(&As[t2 * 8], Ab + (size_t)row2 * K + k0 + c82);
    }
#pragma unroll
    for (int it = 0; it < 4; ++it) {
      int idx = it * 256 + t;
      int row = idx >> 3, c8 = (idx & 7) << 3;
      gld_lds16(&Bs[idx * 8], Bb + (size_t)row * K + k0 + c8);
    }
    __syncthreads();
#pragma unroll
    for (int kk = 0; kk < 2; ++kk) {
      short8 af[2], bq[4];
#pragma unroll
      for (int i = 0; i < 2; ++i)
        af[i] = *(const short8*)&As[(wr * 32 + i * 16 + l16) * 64 + kk * 32 + lg * 8];
#pragma unroll
      for (int j = 0; j < 4; ++j)
        bq[j] = *(const short8*)&Bs[(wc * 64 + j * 16 + l16) * 64 + kk * 32 + lg * 8];
#pragma unroll
      for (int i = 0; i < 2; ++i)
#pragma unroll
        for (int j = 0; j < 4; ++j)
          acc[i][j] = __builtin_amdgcn_mfma_f32_16x16x32_bf16(af[i], bq[j], acc[i][j], 0, 0, 0);
    }
  }
#pragma unroll
  for (int i = 0; i < 2; ++i) {
    int row0 = bm * 64 + wr * 32 + i * 16 + lg * 4;
#pragma unroll
    for (int j = 0; j < 4; ++j) {
      int col = bn * 128 + wc * 64 + j * 16 + l16;
#pragma unroll
      for (int r = 0; r < 4; ++r)
        C[(size_t)(row0 + r) * N + col] = acc[i][j][r];
    }
  }
}

// ---------------------------------------------------------------------------
// Kernel 3: sliding-window flash attention.
// 32x32x16 swapped MFMA + in-register P (round-5 verified math) + LDS-staged
// K/V with DOUBLE BUFFER (one barrier per tile) + T14 reg prefetch + T5.
// Grid (64, 8), 256 threads = 4 waves. Block = 64 q-rows x 2 heads (one kv
// pair). Wave w: head (w>>1), 32-row q-subtile (w&1).
// Fixed-max softmax: p = exp2(s) (scores bounded by RMSNorm), masks on the
// 2 edge tiles only. P rebuilt in-register via pk2 + shfl_xor(32) + select.
// ---------------------------------------------------------------------------
__global__ __launch_bounds__(256) void k_attn(
    const uint16_t* __restrict__ qb,   // [S][HIDDEN], pre-scaled by QSCALE
    const uint16_t* __restrict__ kb,   // [KV][S][64]
    const uint16_t* __restrict__ vtb,  // [KV][64][S]
    const float* __restrict__ sinks,
    uint16_t* __restrict__ ao) {       // [S][HIDDEN]
  __shared__ uint16_t Kl[2][64][72];   // [buf][key][d], +8 pad
  __shared__ uint16_t Vl[2][64][72];   // [buf][d][key]
  const int q0 = (63 - blockIdx.x) * 64;   // long blocks first
  const int hp = blockIdx.y;               // head-pair 0..7
  const int kvh = hp >> 1;
  const int t = threadIdx.x;
  const int lane = t & 63, w = t >> 6;
  const int h = kvh * 4 + (hp & 1) * 2 + (w >> 1);
  const int qbase = q0 + (w & 1) * 32;
  const int l32 = lane & 31, hi = lane >> 5;
  const int qrow = qbase + l32;            // this lane's q-row

  // Q fragments (B operand): bq[s] = Q[qrow][h*64 + s*16 + hi*8 .. +7]
  short8 bq[4];
  {
    const uint16_t* qp = qb + (size_t)qrow * HIDDEN + h * 64 + hi * 8;
    bq[0] = *(const short8*)(qp);
    bq[1] = *(const short8*)(qp + 16);
    bq[2] = *(const short8*)(qp + 32);
    bq[3] = *(const short8*)(qp + 48);
  }

  int kstart = q0 - WINDOW;
  if (kstart < 0) kstart = 0;

  // staging: thread t owns rows r1 = t>>3 and r2 = r1+32, chunk c8 = (t&7)*8
  const int r1 = t >> 3, sc8 = (t & 7) << 3;
  const uint16_t* kp = kb + ((size_t)kvh * S_LEN + r1) * 64 + sc8;          // +key*64
  const uint16_t* kp2 = kp + (size_t)32 * 64;
  const uint16_t* vp = vtb + ((size_t)kvh * 64 + r1) * S_LEN + sc8;         // +key
  const uint16_t* vp2 = vp + (size_t)32 * S_LEN;

  // prologue: tile kstart -> regs -> buf0; prefetch kstart+64
  short8 nk0 = *(const short8*)(kp  + (size_t)kstart * 64);
  short8 nk1 = *(const short8*)(kp2 + (size_t)kstart * 64);
  short8 nv0 = *(const short8*)(vp  + kstart);
  short8 nv1 = *(const short8*)(vp2 + kstart);
  *(short8*)&Kl[0][r1][sc8]      = nk0;
  *(short8*)&Kl[0][r1 + 32][sc8] = nk1;
  *(short8*)&Vl[0][r1][sc8]      = nv0;
  *(short8*)&Vl[0][r1 + 32][sc8] = nv1;
  if (kstart + 64 <= q0) {
    nk0 = *(const short8*)(kp  + (size_t)(kstart + 64) * 64);
    nk1 = *(const short8*)(kp2 + (size_t)(kstart + 64) * 64);
    nv0 = *(const short8*)(vp  + kstart + 64);
    nv1 = *(const short8*)(vp2 + kstart + 64);
  }
  __syncthreads();

  f32x16 acc0 = {}, acc1 = {};
  float lsum = 0.f;
  int ib = 0;

  for (int k0 = kstart; k0 <= q0; k0 += 64, ib ^= 1) {
    // commit prefetched tile (k0+64) into buf ib^1; prefetch k0+128
    if (k0 + 64 <= q0) {
      *(short8*)&Kl[ib ^ 1][r1][sc8]      = nk0;
      *(short8*)&Kl[ib ^ 1][r1 + 32][sc8] = nk1;
      *(short8*)&Vl[ib ^ 1][r1][sc8]      = nv0;
      *(short8*)&Vl[ib ^ 1][r1 + 32][sc8] = nv1;
      if (k0 + 128 <= q0) {
        nk0 = *(const short8*)(kp  + (size_t)(k0 + 128) * 64);
        nk1 = *(const short8*)(kp2 + (size_t)(k0 + 128) * 64);
        nv0 = *(const short8*)(vp  + k0 + 128);
        nv1 = *(const short8*)(vp2 + k0 + 128);
      }
    }

    const bool edge = (k0 == q0) || (k0 == q0 - WINDOW);
#pragma unroll
    for (int c = 0; c < 2; ++c) {            // two 32-key subtiles
      // S^T = K Q^T: D[key][q]; A = K from LDS
      f32x16 st = {};
      __builtin_amdgcn_s_setprio(1);
#pragma unroll
      for (int s = 0; s < 4; ++s) {
        short8 ak = *(const short8*)&Kl[ib][c * 32 + l32][s * 16 + hi * 8];
        st = __builtin_amdgcn_mfma_f32_32x32x16_bf16(ak, bq[s], st, 0, 0, 0);
      }
      __builtin_amdgcn_s_setprio(0);
      // softmax: p = exp2(st); key = k0 + c*32 + 4*hi + (r&3) + 8*(r>>2)
      float pp[16];
      if (edge) {
#pragma unroll
        for (int r = 0; r < 16; ++r) {
          int key = k0 + c * 32 + 4 * hi + (r & 3) + 8 * (r >> 2);
          bool ok = (key <= qrow) && (key + WINDOW > qrow);
          pp[r] = ok ? exp2f(st[r]) : 0.f;
        }
      } else {
#pragma unroll
        for (int r = 0; r < 16; ++r) pp[r] = exp2f(st[r]);
      }
#pragma unroll
      for (int r = 0; r < 16; ++r) lsum += pp[r];
      // pack to bf16 pairs
      uint32_t wvp[8];
#pragma unroll
      for (int i = 0; i < 8; ++i) wvp[i] = pk2(pp[2 * i], pp[2 * i + 1]);
      // PV: two 16-key steps; A-frag rebuilt in-register
#pragma unroll
      for (int half = 0; half < 2; ++half) {
        uint32_t x0 = wvp[half * 4 + 0], x1 = wvp[half * 4 + 1];
        uint32_t x2 = wvp[half * 4 + 2], x3 = wvp[half * 4 + 3];
        uint32_t p0 = (uint32_t)__shfl_xor((int)x0, 32);
        uint32_t p1 = (uint32_t)__shfl_xor((int)x1, 32);
        uint32_t p2 = (uint32_t)__shfl_xor((int)x2, 32);
        uint32_t p3 = (uint32_t)__shfl_xor((int)x3, 32);
        uint4 au = { hi ? p2 : x0, hi ? p3 : x1, hi ? x2 : p0, hi ? x3 : p1 };
        short8 pa = __builtin_bit_cast(short8, au);
        short8 bv0 = *(const short8*)&Vl[ib][l32][c * 32 + half * 16 + hi * 8];
        short8 bv1 = *(const short8*)&Vl[ib][32 + l32][c * 32 + half * 16 + hi * 8];
        __builtin_amdgcn_s_setprio(1);
        acc0 = __builtin_amdgcn_mfma_f32_32x32x16_bf16(pa, bv0, acc0, 0, 0, 0);
        acc1 = __builtin_amdgcn_mfma_f32_32x32x16_bf16(pa, bv1, acc1, 0, 0, 0);
        __builtin_amdgcn_s_setprio(0);
      }
    }
    __syncthreads();   // everyone done with buf[ib]; commit of buf[ib^1] visible
  }

  // denominator: pair (l, l+32) covers all keys of each subtile
  lsum += __shfl_xor(lsum, 32);
  float inv = 1.0f / (lsum + exp2f(sinks[h] * L2E));   // lane holds q = l32
  // acc rows: q-local = (r&3) + 8*(r>>2) + 4*hi; cols: d = {0,32} + l32
#pragma unroll
  for (int r = 0; r < 16; ++r) {
    int rloc = (r & 3) + 8 * (r >> 2) + 4 * hi;
    float rd = __shfl(inv, rloc);
    size_t base = (size_t)(qbase + rloc) * HIDDEN + h * 64 + l32;
    ao[base]      = f2bf(acc0[r] * rd);
    ao[base + 32] = f2bf(acc1[r] * rd);
  }
}

// ---------------------------------------------------------------------------
// Launch. Workspace layout (~33 MB of d_ws):
//   [0,8M)    xb      bf16 x            [4096][1024]
//   [8,11M)   wqkvb   bf16 wq|wk|wv     [1536][1024]
//   [11,13M)  wob     bf16 wo           [1024][1024]
//   [13,21M)  qsc     bf16 q (scaled)   [4096][1024]
//   [21,23M)  kbf     bf16 k            [4][4096][64]
//   [23,25M)  vtb     bf16 v^T          [4][64][4096]
//   [25,33M)  aob     bf16 attn out     [4096][1024]
// ---------------------------------------------------------------------------
extern "C" void kernel_launch(void* const* d_in, const int* in_sizes, int n_in,
                              void* d_out, int out_size, void* d_ws, size_t ws_size,
                              hipStream_t stream) {
  const float* x     = (const float*)d_in[0];
  const float* cosb  = (const float*)d_in[1];
  const float* sinb  = (const float*)d_in[2];
  const float* wq    = (const float*)d_in[3];
  const float* wk    = (const float*)d_in[4];
  const float* wv    = (const float*)d_in[5];
  const float* wo    = (const float*)d_in[6];
  const float* qnw   = (const float*)d_in[7];
  const float* knw   = (const float*)d_in[8];
  const float* sinks = (const float*)d_in[9];
  float* out = (float*)d_out;

  char* ws = (char*)d_ws;
  uint16_t* xb    = (uint16_t*)(ws);
  uint16_t* wqkvb = (uint16_t*)(ws + (8ll  << 20));
  uint16_t* wob   = (uint16_t*)(ws + (11ll << 20));
  uint16_t* qsc   = (uint16_t*)(ws + (13ll << 20));
  uint16_t* kbf   = (uint16_t*)(ws + (21ll << 20));
  uint16_t* vtb   = (uint16_t*)(ws + (23ll << 20));
  uint16_t* aob   = (uint16_t*)(ws + (25ll << 20));

  k_tobf16  <<<6656, 256, 0, stream>>>(x, wq, wk, wv, wo, xb, wqkvb, wob);
  k_gemm_qkv<<<dim3(64, 12), 256, 0, stream>>>(xb, wqkvb, cosb, sinb, qnw, knw,
                                               qsc, kbf, vtb);
  k_attn    <<<dim3(64, 8), 256, 0, stream>>>(qsc, kbf, vtb, sinks, aob);
  k_gemm_bf16<<<dim3(64, 8), 256, 0, stream>>>(aob, wob, out, 1024, 1024);
}

// Round 8
// 81.127 us; speedup vs baseline: 1.0439x; 1.0439x over previous
//
#include <hip/hip_runtime.h>
#include <hip/hip_bf16.h>
#include <stdint.h>

// Problem constants
#define S_LEN   4096
#define HIDDEN  1024
#define NHEAD   16
#define NKV     4
#define HD      64
#define WINDOW  512
#define L2E     1.4426950408889634f
#define QSCALE  (0.125f * L2E)

using short8 = __attribute__((ext_vector_type(8))) short;
using f32x4  = __attribute__((ext_vector_type(4))) float;

// fp32 -> bf16, round-to-nearest-even
__device__ __forceinline__ uint16_t f2bf(float f) {
  uint32_t u = __builtin_bit_cast(uint32_t, f);
  u += 0x7fffu + ((u >> 16) & 1u);
  return (uint16_t)(u >> 16);
}
// round-to-nearest (ties up) — P values only (all >=0, bias ~2^-17)
__device__ __forceinline__ uint16_t f2bf_rn(float f) {
  uint32_t u = __builtin_bit_cast(uint32_t, f);
  return (uint16_t)((u + 0x8000u) >> 16);
}
__device__ __forceinline__ uint32_t pk2(float a, float b) {
  return (uint32_t)f2bf_rn(a) | ((uint32_t)f2bf_rn(b) << 16);
}

// async global->LDS, 16B per lane. LDS dest must be wave-uniform base + lane*16.
__device__ __forceinline__ void gld_lds16(void* lds, const void* g) {
  __builtin_amdgcn_global_load_lds(
      (const __attribute__((address_space(1))) char*)g,
      (__attribute__((address_space(3))) char*)lds, 16, 0, 0);
}

// ---------------------------------------------------------------------------
// Kernel 1: pack x, wq|wk|wv (concat rows), wo to bf16
// ---------------------------------------------------------------------------
__global__ __launch_bounds__(256) void k_tobf16(
    const float* __restrict__ x, const float* __restrict__ wq,
    const float* __restrict__ wk, const float* __restrict__ wv,
    const float* __restrict__ wo,
    uint16_t* __restrict__ xb, uint16_t* __restrict__ wqkvb,
    uint16_t* __restrict__ wob) {
  int i = blockIdx.x * 256 + threadIdx.x;  // one float4 per thread, exact grid
  const float4* src; uint16_t* dst; int off;
  if (i < 1048576)      { src = (const float4*)x;  dst = xb;                off = i; }
  else if (i < 1310720) { src = (const float4*)wq; dst = wqkvb;             off = i - 1048576; }
  else if (i < 1376256) { src = (const float4*)wk; dst = wqkvb + 1024*1024; off = i - 1310720; }
  else if (i < 1441792) { src = (const float4*)wv; dst = wqkvb + 1280*1024; off = i - 1376256; }
  else                  { src = (const float4*)wo; dst = wob;               off = i - 1441792; }
  float4 v = src[off];
  ushort4 o = { f2bf(v.x), f2bf(v.y), f2bf(v.z), f2bf(v.w) };
  *(ushort4*)(dst + (size_t)off * 4) = o;
}

// ---------------------------------------------------------------------------
// Kernel 2: QKV GEMM with fused RMSNorm + RoPE + cast + layout epilogue.
// BM=64, BN=128, BK=64; 4 waves in 2x2, wave tile 32x64 (acc[2][4]).
// Flat grid 768 with XCD-pinning swizzle: xcd = bid%8, bm = xcd + 8*(i%8),
// bn = i/8 (i = bid/8). Each XCD re-reads its 8 A-panels (1MB) + B (3MB)
// from its own L2.
// ---------------------------------------------------------------------------
__global__ __launch_bounds__(256) void k_gemm_qkv(
    const uint16_t* __restrict__ A, const uint16_t* __restrict__ B,
    const float* __restrict__ cosb, const float* __restrict__ sinb,
    const float* __restrict__ qw, const float* __restrict__ kw,
    uint16_t* __restrict__ qout, uint16_t* __restrict__ kout,
    uint16_t* __restrict__ vtout) {
  __shared__ uint16_t As[64 * 64];
  __shared__ uint16_t Bs[128 * 64];
  const int K = 1024;
  const int t = threadIdx.x;
  const int lane = t & 63, w = t >> 6;
  const int wr = w >> 1, wc = w & 1;
  const int l16 = lane & 15, lg = lane >> 4;
  const int bid = blockIdx.x;
  const int xcd = bid & 7, idx = bid >> 3;         // idx in [0,96)
  const int bm = xcd + 8 * (idx & 7);              // [0,64)
  const int bn = idx >> 3;                         // [0,12)
  const uint16_t* Ab = A + (size_t)bm * 64 * K;
  const uint16_t* Bb = B + (size_t)bn * 128 * K;
  f32x4 acc[2][4] = {};
  for (int k0 = 0; k0 < K; k0 += 64) {
    __syncthreads();
    {  // stage A: 64x64 = 512 16B-chunks -> 2/thread
      int row = t >> 3, c8 = (t & 7) << 3;
      gld_lds16(&As[t * 8], Ab + (size_t)row * K + k0 + c8);
      int t2 = t + 256, row2 = t2 >> 3, c82 = (t2 & 7) << 3;
      gld_lds16(&As[t2 * 8], Ab + (size_t)row2 * K + k0 + c82);
    }
#pragma unroll
    for (int it = 0; it < 4; ++it) {  // stage B: 128x64 -> 4/thread
      int idx2 = it * 256 + t;
      int row = idx2 >> 3, c8 = (idx2 & 7) << 3;
      gld_lds16(&Bs[idx2 * 8], Bb + (size_t)row * K + k0 + c8);
    }
    __syncthreads();
#pragma unroll
    for (int kk = 0; kk < 2; ++kk) {
      short8 af[2], bq[4];
#pragma unroll
      for (int i = 0; i < 2; ++i)
        af[i] = *(const short8*)&As[(wr * 32 + i * 16 + l16) * 64 + kk * 32 + lg * 8];
#pragma unroll
      for (int j = 0; j < 4; ++j)
        bq[j] = *(const short8*)&Bs[(wc * 64 + j * 16 + l16) * 64 + kk * 32 + lg * 8];
#pragma unroll
      for (int i = 0; i < 2; ++i)
#pragma unroll
        for (int j = 0; j < 4; ++j)
          acc[i][j] = __builtin_amdgcn_mfma_f32_16x16x32_bf16(af[i], bq[j], acc[i][j], 0, 0, 0);
    }
  }

  // ---- fused epilogue ----
  const int hg = bn * 2 + wc;   // global 64-wide head slot, uniform per wave
  if (hg >= 20) {               // V: cast + transposed store
    const int kvh = hg - 20;
#pragma unroll
    for (int i = 0; i < 2; ++i) {
      int row0 = bm * 64 + wr * 32 + i * 16 + lg * 4;
#pragma unroll
      for (int j = 0; j < 4; ++j) {
        int d = j * 16 + l16;
        ushort4 o = { f2bf(acc[i][j][0]), f2bf(acc[i][j][1]),
                      f2bf(acc[i][j][2]), f2bf(acc[i][j][3]) };
        *(ushort4*)(vtout + (size_t)(kvh * 64 + d) * S_LEN + row0) = o;
      }
    }
    return;
  }
  // Q/K: RMSNorm + RoPE
  const float* nw = (hg < 16) ? qw : kw;
  float wgt[4];
#pragma unroll
  for (int j = 0; j < 4; ++j) wgt[j] = nw[j * 16 + l16];
#pragma unroll
  for (int i = 0; i < 2; ++i) {
    int row0 = bm * 64 + wr * 32 + i * 16 + lg * 4;
    float qn[4][4];
#pragma unroll
    for (int r = 0; r < 4; ++r) {
      float ss = acc[i][0][r] * acc[i][0][r] + acc[i][1][r] * acc[i][1][r]
               + acc[i][2][r] * acc[i][2][r] + acc[i][3][r] * acc[i][3][r];
      ss += __shfl_xor(ss, 1);
      ss += __shfl_xor(ss, 2);
      ss += __shfl_xor(ss, 4);
      ss += __shfl_xor(ss, 8);
      float inv = rsqrtf(ss * (1.0f / 64.0f) + 1e-5f);
#pragma unroll
      for (int j = 0; j < 4; ++j) qn[j][r] = acc[i][j][r] * inv * wgt[j];
    }
#pragma unroll
    for (int j = 0; j < 4; ++j) {
      int d = j * 16 + l16;
#pragma unroll
      for (int r = 0; r < 4; ++r) {
        int row = row0 + r;
        float rot = (j < 2) ? -qn[j + 2][r] : qn[j - 2][r];   // rotate_half
        float o = qn[j][r] * cosb[row * 64 + d] + rot * sinb[row * 64 + d];
        if (hg < 16)
          qout[(size_t)row * HIDDEN + hg * 64 + d] = f2bf(o * QSCALE);
        else
          kout[((size_t)(hg - 16) * S_LEN + row) * 64 + d] = f2bf(o);
      }
    }
  }
}

// ---------------------------------------------------------------------------
// Kernel 4: C[M][N] = A[M][K] * B[N][K]^T — output projection (M=4096, N=1024).
// Flat grid 512, XCD-pinned: bm = (bid&7) + 8*((bid>>3)&7), bn = bid>>6.
// ---------------------------------------------------------------------------
__global__ __launch_bounds__(256) void k_gemm_bf16(
    const uint16_t* __restrict__ A, const uint16_t* __restrict__ B,
    float* __restrict__ C, int N, int K) {
  __shared__ uint16_t As[64 * 64];
  __shared__ uint16_t Bs[128 * 64];
  const int t = threadIdx.x;
  const int lane = t & 63, w = t >> 6;
  const int wr = w >> 1, wc = w & 1;
  const int l16 = lane & 15, lg = lane >> 4;
  const int bid = blockIdx.x;
  const int xcd = bid & 7, idx = bid >> 3;         // idx in [0,64)
  const int bm = xcd + 8 * (idx & 7);              // [0,64)
  const int bn = idx >> 3;                         // [0,8)
  const uint16_t* Ab = A + (size_t)bm * 64 * K;
  const uint16_t* Bb = B + (size_t)bn * 128 * K;
  f32x4 acc[2][4] = {};
  for (int k0 = 0; k0 < K; k0 += 64) {
    __syncthreads();
    {
      int row = t >> 3, c8 = (t & 7) << 3;
      gld_lds16(&As[t * 8], Ab + (size_t)row * K + k0 + c8);
      int t2 = t + 256, row2 = t2 >> 3, c82 = (t2 & 7) << 3;
      gld_lds16(&As[t2 * 8], Ab + (size_t)row2 * K + k0 + c82);
    }
#pragma unroll
    for (int it = 0; it < 4; ++it) {
      int idx2 = it * 256 + t;
      int row = idx2 >> 3, c8 = (idx2 & 7) << 3;
      gld_lds16(&Bs[idx2 * 8], Bb + (size_t)row * K + k0 + c8);
    }
    __syncthreads();
#pragma unroll
    for (int kk = 0; kk < 2; ++kk) {
      short8 af[2], bq[4];
#pragma unroll
      for (int i = 0; i < 2; ++i)
        af[i] = *(const short8*)&As[(wr * 32 + i * 16 + l16) * 64 + kk * 32 + lg * 8];
#pragma unroll
      for (int j = 0; j < 4; ++j)
        bq[j] = *(const short8*)&Bs[(wc * 64 + j * 16 + l16) * 64 + kk * 32 + lg * 8];
#pragma unroll
      for (int i = 0; i < 2; ++i)
#pragma unroll
        for (int j = 0; j < 4; ++j)
          acc[i][j] = __builtin_amdgcn_mfma_f32_16x16x32_bf16(af[i], bq[j], acc[i][j], 0, 0, 0);
    }
  }
#pragma unroll
  for (int i = 0; i < 2; ++i) {
    int row0 = bm * 64 + wr * 32 + i * 16 + lg * 4;
#pragma unroll
    for (int j = 0; j < 4; ++j) {
      int col = bn * 128 + wc * 64 + j * 16 + l16;
#pragma unroll
      for (int r = 0; r < 4; ++r)
        C[(size_t)(row0 + r) * N + col] = acc[i][j][r];
    }
  }
}

// ---------------------------------------------------------------------------
// Kernel 3: sliding-window flash attention (round-6 structure + XCD pinning).
// Flat grid 512, 512 threads = 8 waves. hp = bid&7 -> pinned to one XCD
// (under round-robin dispatch): its 2MB K/V stays L2-resident on that XCD.
// q0 = (63 - bid>>3)*64 (long blocks first). Wave w: head (w>>2), q-sub (w&3).
// SWAPPED QK^T 16x16, T14 reg prefetch, T5 setprio, fixed-max softmax.
// ---------------------------------------------------------------------------
__global__ __launch_bounds__(512) void k_attn(
    const uint16_t* __restrict__ qb,   // [S][HIDDEN], pre-scaled by QSCALE
    const uint16_t* __restrict__ kb,   // [KV][S][64]
    const uint16_t* __restrict__ vtb,  // [KV][64][S]
    const float* __restrict__ sinks,
    uint16_t* __restrict__ ao) {       // [S][HIDDEN]
  __shared__ uint16_t Kl[64][72];      // +8 pad
  __shared__ uint16_t Vl[64][72];      // V^T tile: [d][key]
  __shared__ uint16_t Pl[8][16][72];   // per-wave P: [q(16)][key(64)+pad]
  const int bid = blockIdx.x;
  const int hp = bid & 7;                  // head-pair == XCD id
  const int q0 = (63 - (bid >> 3)) * 64;   // long blocks first
  const int kvh = hp >> 1;
  const int t = threadIdx.x;
  const int lane = t & 63, w = t >> 6;
  const int h = kvh * 4 + (hp & 1) * 2 + (w >> 2);
  const int wq = w & 3;
  const int l16 = lane & 15, lg = lane >> 4;
  const int qrow = q0 + wq * 16 + l16;     // this lane's q-row

  // Q fragment, used as the B operand (n = l16 = q-row)
  short8 bq0, bq1;
  {
    const uint16_t* qp = qb + (size_t)qrow * HIDDEN + h * 64 + lg * 8;
    bq0 = *(const short8*)qp;
    bq1 = *(const short8*)(qp + 32);
  }
  float lsum = 0.f;
  f32x4 acc[4] = {};

  int kstart = q0 - WINDOW;
  if (kstart < 0) kstart = 0;

  // staging: thread t owns (row = t>>3, 16B chunk = t&7) of both tiles
  const int srow = t >> 3, sc8 = (t & 7) << 3;
  const uint16_t* kp = kb + ((size_t)kvh * S_LEN + srow) * 64 + sc8;
  const uint16_t* vp = vtb + ((size_t)kvh * 64 + srow) * S_LEN + sc8;
  // prologue: first tile into regs
  short8 nk = *(const short8*)(kp + (size_t)kstart * 64);
  short8 nv = *(const short8*)(vp + kstart);

  for (int k0 = kstart; k0 <= q0; k0 += 64) {
    __syncthreads();                   // previous tile fully consumed
    *(short8*)&Kl[srow][sc8] = nk;     // commit prefetched tile (vmcnt wait here)
    *(short8*)&Vl[srow][sc8] = nv;
    __syncthreads();
    if (k0 + 64 <= q0) {               // T14: issue next-tile loads NOW
      nk = *(const short8*)(kp + (size_t)(k0 + 64) * 64);
      nv = *(const short8*)(vp + k0 + 64);
    }

    // S^T = K Q^T: D[m=key][n=q]
    f32x4 st[4] = {};
    __builtin_amdgcn_s_setprio(1);
#pragma unroll
    for (int c = 0; c < 4; ++c) {
      short8 ak0 = *(const short8*)&Kl[c * 16 + l16][lg * 8];
      short8 ak1 = *(const short8*)&Kl[c * 16 + l16][32 + lg * 8];
      st[c] = __builtin_amdgcn_mfma_f32_16x16x32_bf16(ak0, bq0, st[c], 0, 0, 0);
      st[c] = __builtin_amdgcn_mfma_f32_16x16x32_bf16(ak1, bq1, st[c], 0, 0, 0);
    }
    __builtin_amdgcn_s_setprio(0);

    // key = k0 + c*16 + lg*4 + r; q-row = qrow (lane-local). Mask edge tiles.
    float p[4][4];
    if (k0 == q0 || k0 == q0 - WINDOW) {
#pragma unroll
      for (int c = 0; c < 4; ++c) {
        int keyb = k0 + c * 16 + lg * 4;
#pragma unroll
        for (int r = 0; r < 4; ++r) {
          int key = keyb + r;
          bool ok = (key <= qrow) && (key + WINDOW > qrow);
          p[c][r] = ok ? exp2f(st[c][r]) : 0.f;
        }
      }
    } else {
#pragma unroll
      for (int c = 0; c < 4; ++c)
#pragma unroll
        for (int r = 0; r < 4; ++r)
          p[c][r] = exp2f(st[c][r]);
    }
#pragma unroll
    for (int c = 0; c < 4; ++c)
      lsum += (p[c][0] + p[c][1]) + (p[c][2] + p[c][3]);

    // pack P (keys consecutive in r) -> [q][key] LDS layout, 8B stores
#pragma unroll
    for (int c = 0; c < 4; ++c) {
      uint2 pw = { pk2(p[c][0], p[c][1]), pk2(p[c][2], p[c][3]) };
      *(uint2*)&Pl[w][l16][c * 16 + lg * 4] = pw;
    }
    asm volatile("s_waitcnt lgkmcnt(0)" ::: "memory");
    short8 pa0 = *(const short8*)&Pl[w][l16][lg * 8];
    short8 pa1 = *(const short8*)&Pl[w][l16][32 + lg * 8];
    __builtin_amdgcn_s_setprio(1);
#pragma unroll
    for (int dt = 0; dt < 4; ++dt) {
      short8 bv0 = *(const short8*)&Vl[dt * 16 + l16][lg * 8];
      short8 bv1 = *(const short8*)&Vl[dt * 16 + l16][32 + lg * 8];
      acc[dt] = __builtin_amdgcn_mfma_f32_16x16x32_bf16(pa0, bv0, acc[dt], 0, 0, 0);
      acc[dt] = __builtin_amdgcn_mfma_f32_16x16x32_bf16(pa1, bv1, acc[dt], 0, 0, 0);
    }
    __builtin_amdgcn_s_setprio(0);
  }

  // lsum: reduce across the 4 lg-groups (lanes sharing l16), add sink
  lsum += __shfl_xor(lsum, 16);
  lsum += __shfl_xor(lsum, 32);
  float sk = exp2f(sinks[h] * L2E);
  float inv = 1.0f / (lsum + sk);     // lane (l16,lg) holds inv for local row l16
  // acc rows are local row lg*4+r -> fetch inv from lane (lg*4+r)
#pragma unroll
  for (int r = 0; r < 4; ++r) {
    float rd = __shfl(inv, lg * 4 + r);
    int row = q0 + wq * 16 + lg * 4 + r;
#pragma unroll
    for (int dt = 0; dt < 4; ++dt)
      ao[(size_t)row * HIDDEN + h * 64 + dt * 16 + l16] = f2bf(acc[dt][r] * rd);
  }
}

// ---------------------------------------------------------------------------
// Launch. Workspace layout (~33 MB of d_ws):
//   [0,8M)    xb      bf16 x            [4096][1024]
//   [8,11M)   wqkvb   bf16 wq|wk|wv     [1536][1024]
//   [11,13M)  wob     bf16 wo           [1024][1024]
//   [13,21M)  qsc     bf16 q (scaled)   [4096][1024]
//   [21,23M)  kbf     bf16 k            [4][4096][64]
//   [23,25M)  vtb     bf16 v^T          [4][64][4096]
//   [25,33M)  aob     bf16 attn out     [4096][1024]
// ---------------------------------------------------------------------------
extern "C" void kernel_launch(void* const* d_in, const int* in_sizes, int n_in,
                              void* d_out, int out_size, void* d_ws, size_t ws_size,
                              hipStream_t stream) {
  const float* x     = (const float*)d_in[0];
  const float* cosb  = (const float*)d_in[1];
  const float* sinb  = (const float*)d_in[2];
  const float* wq    = (const float*)d_in[3];
  const float* wk    = (const float*)d_in[4];
  const float* wv    = (const float*)d_in[5];
  const float* wo    = (const float*)d_in[6];
  const float* qnw   = (const float*)d_in[7];
  const float* knw   = (const float*)d_in[8];
  const float* sinks = (const float*)d_in[9];
  float* out = (float*)d_out;

  char* ws = (char*)d_ws;
  uint16_t* xb    = (uint16_t*)(ws);
  uint16_t* wqkvb = (uint16_t*)(ws + (8ll  << 20));
  uint16_t* wob   = (uint16_t*)(ws + (11ll << 20));
  uint16_t* qsc   = (uint16_t*)(ws + (13ll << 20));
  uint16_t* kbf   = (uint16_t*)(ws + (21ll << 20));
  uint16_t* vtb   = (uint16_t*)(ws + (23ll << 20));
  uint16_t* aob   = (uint16_t*)(ws + (25ll << 20));

  k_tobf16  <<<6656, 256, 0, stream>>>(x, wq, wk, wv, wo, xb, wqkvb, wob);
  k_gemm_qkv<<<768, 256, 0, stream>>>(xb, wqkvb, cosb, sinb, qnw, knw,
                                      qsc, kbf, vtb);
  k_attn    <<<512, 512, 0, stream>>>(qsc, kbf, vtb, sinks, aob);
  k_gemm_bf16<<<512, 256, 0, stream>>>(aob, wob, out, 1024, 1024);
}

// Round 9
// 80.843 us; speedup vs baseline: 1.0475x; 1.0035x over previous
//
#include <hip/hip_runtime.h>
#include <hip/hip_bf16.h>
#include <stdint.h>

// Problem constants
#define S_LEN   4096
#define HIDDEN  1024
#define NHEAD   16
#define NKV     4
#define HD      64
#define WINDOW  512
#define L2E     1.4426950408889634f
#define QSCALE  (0.125f * L2E)

using short8 = __attribute__((ext_vector_type(8))) short;
using f32x4  = __attribute__((ext_vector_type(4))) float;

// fp32 -> bf16, round-to-nearest-even
__device__ __forceinline__ uint16_t f2bf(float f) {
  uint32_t u = __builtin_bit_cast(uint32_t, f);
  u += 0x7fffu + ((u >> 16) & 1u);
  return (uint16_t)(u >> 16);
}
// round-to-nearest (ties up) — P values only (all >=0, bias ~2^-17)
__device__ __forceinline__ uint16_t f2bf_rn(float f) {
  uint32_t u = __builtin_bit_cast(uint32_t, f);
  return (uint16_t)((u + 0x8000u) >> 16);
}
__device__ __forceinline__ uint32_t pk2(float a, float b) {
  return (uint32_t)f2bf_rn(a) | ((uint32_t)f2bf_rn(b) << 16);
}

// async global->LDS, 16B per lane. LDS dest must be wave-uniform base + lane*16.
__device__ __forceinline__ void gld_lds16(void* lds, const void* g) {
  __builtin_amdgcn_global_load_lds(
      (const __attribute__((address_space(1))) char*)g,
      (__attribute__((address_space(3))) char*)lds, 16, 0, 0);
}

// ---------------------------------------------------------------------------
// Kernel 1: pack x, wq|wk|wv (concat rows), wo to bf16
// ---------------------------------------------------------------------------
__global__ __launch_bounds__(256) void k_tobf16(
    const float* __restrict__ x, const float* __restrict__ wq,
    const float* __restrict__ wk, const float* __restrict__ wv,
    const float* __restrict__ wo,
    uint16_t* __restrict__ xb, uint16_t* __restrict__ wqkvb,
    uint16_t* __restrict__ wob) {
  int i = blockIdx.x * 256 + threadIdx.x;  // one float4 per thread, exact grid
  const float4* src; uint16_t* dst; int off;
  if (i < 1048576)      { src = (const float4*)x;  dst = xb;                off = i; }
  else if (i < 1310720) { src = (const float4*)wq; dst = wqkvb;             off = i - 1048576; }
  else if (i < 1376256) { src = (const float4*)wk; dst = wqkvb + 1024*1024; off = i - 1310720; }
  else if (i < 1441792) { src = (const float4*)wv; dst = wqkvb + 1280*1024; off = i - 1376256; }
  else                  { src = (const float4*)wo; dst = wob;               off = i - 1441792; }
  float4 v = src[off];
  ushort4 o = { f2bf(v.x), f2bf(v.y), f2bf(v.z), f2bf(v.w) };
  *(ushort4*)(dst + (size_t)off * 4) = o;
}

// ---------------------------------------------------------------------------
// Kernel 2: QKV GEMM with fused RMSNorm + RoPE + cast + layout epilogue.
// BM=64, BN=128, BK=64; 4 waves in 2x2, wave tile 32x64 (acc[2][4]).
// Flat grid 768 with XCD-pinning swizzle.
// ---------------------------------------------------------------------------
__global__ __launch_bounds__(256) void k_gemm_qkv(
    const uint16_t* __restrict__ A, const uint16_t* __restrict__ B,
    const float* __restrict__ cosb, const float* __restrict__ sinb,
    const float* __restrict__ qw, const float* __restrict__ kw,
    uint16_t* __restrict__ qout, uint16_t* __restrict__ kout,
    uint16_t* __restrict__ vtout) {
  __shared__ uint16_t As[64 * 64];
  __shared__ uint16_t Bs[128 * 64];
  const int K = 1024;
  const int t = threadIdx.x;
  const int lane = t & 63, w = t >> 6;
  const int wr = w >> 1, wc = w & 1;
  const int l16 = lane & 15, lg = lane >> 4;
  const int bid = blockIdx.x;
  const int xcd = bid & 7, idx = bid >> 3;         // idx in [0,96)
  const int bm = xcd + 8 * (idx & 7);              // [0,64)
  const int bn = idx >> 3;                         // [0,12)
  const uint16_t* Ab = A + (size_t)bm * 64 * K;
  const uint16_t* Bb = B + (size_t)bn * 128 * K;
  f32x4 acc[2][4] = {};
  for (int k0 = 0; k0 < K; k0 += 64) {
    __syncthreads();
    {  // stage A: 64x64 = 512 16B-chunks -> 2/thread
      int row = t >> 3, c8 = (t & 7) << 3;
      gld_lds16(&As[t * 8], Ab + (size_t)row * K + k0 + c8);
      int t2 = t + 256, row2 = t2 >> 3, c82 = (t2 & 7) << 3;
      gld_lds16(&As[t2 * 8], Ab + (size_t)row2 * K + k0 + c82);
    }
#pragma unroll
    for (int it = 0; it < 4; ++it) {  // stage B: 128x64 -> 4/thread
      int idx2 = it * 256 + t;
      int row = idx2 >> 3, c8 = (idx2 & 7) << 3;
      gld_lds16(&Bs[idx2 * 8], Bb + (size_t)row * K + k0 + c8);
    }
    __syncthreads();
#pragma unroll
    for (int kk = 0; kk < 2; ++kk) {
      short8 af[2], bq[4];
#pragma unroll
      for (int i = 0; i < 2; ++i)
        af[i] = *(const short8*)&As[(wr * 32 + i * 16 + l16) * 64 + kk * 32 + lg * 8];
#pragma unroll
      for (int j = 0; j < 4; ++j)
        bq[j] = *(const short8*)&Bs[(wc * 64 + j * 16 + l16) * 64 + kk * 32 + lg * 8];
#pragma unroll
      for (int i = 0; i < 2; ++i)
#pragma unroll
        for (int j = 0; j < 4; ++j)
          acc[i][j] = __builtin_amdgcn_mfma_f32_16x16x32_bf16(af[i], bq[j], acc[i][j], 0, 0, 0);
    }
  }

  // ---- fused epilogue ----
  const int hg = bn * 2 + wc;   // global 64-wide head slot, uniform per wave
  if (hg >= 20) {               // V: cast + transposed store
    const int kvh = hg - 20;
#pragma unroll
    for (int i = 0; i < 2; ++i) {
      int row0 = bm * 64 + wr * 32 + i * 16 + lg * 4;
#pragma unroll
      for (int j = 0; j < 4; ++j) {
        int d = j * 16 + l16;
        ushort4 o = { f2bf(acc[i][j][0]), f2bf(acc[i][j][1]),
                      f2bf(acc[i][j][2]), f2bf(acc[i][j][3]) };
        *(ushort4*)(vtout + (size_t)(kvh * 64 + d) * S_LEN + row0) = o;
      }
    }
    return;
  }
  // Q/K: RMSNorm + RoPE
  const float* nw = (hg < 16) ? qw : kw;
  float wgt[4];
#pragma unroll
  for (int j = 0; j < 4; ++j) wgt[j] = nw[j * 16 + l16];
#pragma unroll
  for (int i = 0; i < 2; ++i) {
    int row0 = bm * 64 + wr * 32 + i * 16 + lg * 4;
    float qn[4][4];
#pragma unroll
    for (int r = 0; r < 4; ++r) {
      float ss = acc[i][0][r] * acc[i][0][r] + acc[i][1][r] * acc[i][1][r]
               + acc[i][2][r] * acc[i][2][r] + acc[i][3][r] * acc[i][3][r];
      ss += __shfl_xor(ss, 1);
      ss += __shfl_xor(ss, 2);
      ss += __shfl_xor(ss, 4);
      ss += __shfl_xor(ss, 8);
      float inv = rsqrtf(ss * (1.0f / 64.0f) + 1e-5f);
#pragma unroll
      for (int j = 0; j < 4; ++j) qn[j][r] = acc[i][j][r] * inv * wgt[j];
    }
#pragma unroll
    for (int j = 0; j < 4; ++j) {
      int d = j * 16 + l16;
#pragma unroll
      for (int r = 0; r < 4; ++r) {
        int row = row0 + r;
        float rot = (j < 2) ? -qn[j + 2][r] : qn[j - 2][r];   // rotate_half
        float o = qn[j][r] * cosb[row * 64 + d] + rot * sinb[row * 64 + d];
        if (hg < 16)
          qout[(size_t)row * HIDDEN + hg * 64 + d] = f2bf(o * QSCALE);
        else
          kout[((size_t)(hg - 16) * S_LEN + row) * 64 + d] = f2bf(o);
      }
    }
  }
}

// ---------------------------------------------------------------------------
// Kernel 4: C[M][N] = A[M][K] * B[N][K]^T — output projection (M=4096, N=1024).
// Flat grid 512, XCD-pinned.
// ---------------------------------------------------------------------------
__global__ __launch_bounds__(256) void k_gemm_bf16(
    const uint16_t* __restrict__ A, const uint16_t* __restrict__ B,
    float* __restrict__ C, int N, int K) {
  __shared__ uint16_t As[64 * 64];
  __shared__ uint16_t Bs[128 * 64];
  const int t = threadIdx.x;
  const int lane = t & 63, w = t >> 6;
  const int wr = w >> 1, wc = w & 1;
  const int l16 = lane & 15, lg = lane >> 4;
  const int bid = blockIdx.x;
  const int xcd = bid & 7, idx = bid >> 3;         // idx in [0,64)
  const int bm = xcd + 8 * (idx & 7);              // [0,64)
  const int bn = idx >> 3;                         // [0,8)
  const uint16_t* Ab = A + (size_t)bm * 64 * K;
  const uint16_t* Bb = B + (size_t)bn * 128 * K;
  f32x4 acc[2][4] = {};
  for (int k0 = 0; k0 < K; k0 += 64) {
    __syncthreads();
    {
      int row = t >> 3, c8 = (t & 7) << 3;
      gld_lds16(&As[t * 8], Ab + (size_t)row * K + k0 + c8);
      int t2 = t + 256, row2 = t2 >> 3, c82 = (t2 & 7) << 3;
      gld_lds16(&As[t2 * 8], Ab + (size_t)row2 * K + k0 + c82);
    }
#pragma unroll
    for (int it = 0; it < 4; ++it) {
      int idx2 = it * 256 + t;
      int row = idx2 >> 3, c8 = (idx2 & 7) << 3;
      gld_lds16(&Bs[idx2 * 8], Bb + (size_t)row * K + k0 + c8);
    }
    __syncthreads();
#pragma unroll
    for (int kk = 0; kk < 2; ++kk) {
      short8 af[2], bq[4];
#pragma unroll
      for (int i = 0; i < 2; ++i)
        af[i] = *(const short8*)&As[(wr * 32 + i * 16 + l16) * 64 + kk * 32 + lg * 8];
#pragma unroll
      for (int j = 0; j < 4; ++j)
        bq[j] = *(const short8*)&Bs[(wc * 64 + j * 16 + l16) * 64 + kk * 32 + lg * 8];
#pragma unroll
      for (int i = 0; i < 2; ++i)
#pragma unroll
        for (int j = 0; j < 4; ++j)
          acc[i][j] = __builtin_amdgcn_mfma_f32_16x16x32_bf16(af[i], bq[j], acc[i][j], 0, 0, 0);
    }
  }
#pragma unroll
  for (int i = 0; i < 2; ++i) {
    int row0 = bm * 64 + wr * 32 + i * 16 + lg * 4;
#pragma unroll
    for (int j = 0; j < 4; ++j) {
      int col = bn * 128 + wc * 64 + j * 16 + l16;
#pragma unroll
      for (int r = 0; r < 4; ++r)
        C[(size_t)(row0 + r) * N + col] = acc[i][j][r];
    }
  }
}

// ---------------------------------------------------------------------------
// Kernel 3: sliding-window flash attention.
// Round-6 compute structure + async gld_lds staging + XOR-swizzled [64][64]
// tiles (swizzle applied on the per-lane GLOBAL source address — m173/T2:
// LDS col16 c of row r holds global col16 c^(r&7); reads XOR with l16&7)
// + double-buffered K/V -> ONE barrier per tile.
// Flat grid 512, 512 threads = 8 waves. Block = 64 q-rows x 2 heads of one
// kv group. Wave w: head (w>>2), q-subtile (w&3). Swapped QK^T 16x16,
// fixed-max softmax (p = exp2(s), scores bounded by RMSNorm), T5 setprio.
// ---------------------------------------------------------------------------
__global__ __launch_bounds__(512) void k_attn(
    const uint16_t* __restrict__ qb,   // [S][HIDDEN], pre-scaled by QSCALE
    const uint16_t* __restrict__ kb,   // [KV][S][64]
    const uint16_t* __restrict__ vtb,  // [KV][64][S]
    const float* __restrict__ sinks,
    uint16_t* __restrict__ ao) {       // [S][HIDDEN]
  __shared__ uint16_t Kl[2][64][64];   // [buf][key][d], XOR-swizzled cols
  __shared__ uint16_t Vl[2][64][64];   // [buf][d][key], XOR-swizzled cols
  __shared__ uint16_t Pl[8][16][72];   // per-wave P: [q(16)][key(64)+pad]
  const int bid = blockIdx.x;
  const int hp = bid & 7;                  // head-pair
  const int q0 = (63 - (bid >> 3)) * 64;   // long blocks first
  const int kvh = hp >> 1;
  const int t = threadIdx.x;
  const int lane = t & 63, w = t >> 6;
  const int h = kvh * 4 + (hp & 1) * 2 + (w >> 2);
  const int wq = w & 3;
  const int l16 = lane & 15, lg = lane >> 4;
  const int qrow = q0 + wq * 16 + l16;     // this lane's q-row
  const int sw = l16 & 7;                  // read-side swizzle key

  // Q fragment, used as the B operand (n = l16 = q-row)
  short8 bq0, bq1;
  {
    const uint16_t* qp = qb + (size_t)qrow * HIDDEN + h * 64 + lg * 8;
    bq0 = *(const short8*)qp;
    bq1 = *(const short8*)(qp + 32);
  }
  float lsum = 0.f;
  f32x4 acc[4] = {};

  int kstart = q0 - WINDOW;
  if (kstart < 0) kstart = 0;

  // staging: thread t fills LDS row t>>3, col16 t&7; source col16 XOR'd.
  const int srow = t >> 3;
  const int scol = ((t & 7) ^ (srow & 7)) << 3;   // swizzled source col (elems)
  const uint16_t* kp = kb + ((size_t)kvh * S_LEN + srow) * 64 + scol;  // +k0*64
  const uint16_t* vp = vtb + ((size_t)kvh * 64 + srow) * S_LEN + scol; // +k0

  // prologue: stage first tile into buf 0
  gld_lds16(&Kl[0][0][0] + (size_t)t * 8, kp + (size_t)kstart * 64);
  gld_lds16(&Vl[0][0][0] + (size_t)t * 8, vp + kstart);
  __syncthreads();   // implicit vmcnt(0) drain: buf0 ready

  int ib = 0;
  for (int k0 = kstart; k0 <= q0; k0 += 64, ib ^= 1) {
    if (k0 + 64 <= q0) {   // async prefetch next tile; lands during compute
      gld_lds16(&Kl[ib ^ 1][0][0] + (size_t)t * 8, kp + (size_t)(k0 + 64) * 64);
      gld_lds16(&Vl[ib ^ 1][0][0] + (size_t)t * 8, vp + k0 + 64);
    }

    // S^T = K Q^T: D[m=key][n=q]; K read swizzled
    f32x4 st[4] = {};
    __builtin_amdgcn_s_setprio(1);
#pragma unroll
    for (int c = 0; c < 4; ++c) {
      short8 ak0 = *(const short8*)&Kl[ib][c * 16 + l16][(lg ^ sw) * 8];
      short8 ak1 = *(const short8*)&Kl[ib][c * 16 + l16][((lg + 4) ^ sw) * 8];
      st[c] = __builtin_amdgcn_mfma_f32_16x16x32_bf16(ak0, bq0, st[c], 0, 0, 0);
      st[c] = __builtin_amdgcn_mfma_f32_16x16x32_bf16(ak1, bq1, st[c], 0, 0, 0);
    }
    __builtin_amdgcn_s_setprio(0);

    // key = k0 + c*16 + lg*4 + r; q-row = qrow (lane-local). Mask edge tiles.
    float p[4][4];
    if (k0 == q0 || k0 == q0 - WINDOW) {
#pragma unroll
      for (int c = 0; c < 4; ++c) {
        int keyb = k0 + c * 16 + lg * 4;
#pragma unroll
        for (int r = 0; r < 4; ++r) {
          int key = keyb + r;
          bool ok = (key <= qrow) && (key + WINDOW > qrow);
          p[c][r] = ok ? exp2f(st[c][r]) : 0.f;
        }
      }
    } else {
#pragma unroll
      for (int c = 0; c < 4; ++c)
#pragma unroll
        for (int r = 0; r < 4; ++r)
          p[c][r] = exp2f(st[c][r]);
    }
#pragma unroll
    for (int c = 0; c < 4; ++c)
      lsum += (p[c][0] + p[c][1]) + (p[c][2] + p[c][3]);

    // pack P (keys consecutive in r) -> [q][key] LDS layout, 8B stores
#pragma unroll
    for (int c = 0; c < 4; ++c) {
      uint2 pw = { pk2(p[c][0], p[c][1]), pk2(p[c][2], p[c][3]) };
      *(uint2*)&Pl[w][l16][c * 16 + lg * 4] = pw;
    }
    asm volatile("s_waitcnt lgkmcnt(0)" ::: "memory");
    short8 pa0 = *(const short8*)&Pl[w][l16][lg * 8];
    short8 pa1 = *(const short8*)&Pl[w][l16][32 + lg * 8];
    __builtin_amdgcn_s_setprio(1);
#pragma unroll
    for (int dt = 0; dt < 4; ++dt) {
      short8 bv0 = *(const short8*)&Vl[ib][dt * 16 + l16][(lg ^ sw) * 8];
      short8 bv1 = *(const short8*)&Vl[ib][dt * 16 + l16][((lg + 4) ^ sw) * 8];
      acc[dt] = __builtin_amdgcn_mfma_f32_16x16x32_bf16(pa0, bv0, acc[dt], 0, 0, 0);
      acc[dt] = __builtin_amdgcn_mfma_f32_16x16x32_bf16(pa1, bv1, acc[dt], 0, 0, 0);
    }
    __builtin_amdgcn_s_setprio(0);

    // single barrier: all waves done reading buf[ib]; prefetch (vmcnt) drained
    __syncthreads();
  }

  // lsum: reduce across the 4 lg-groups (lanes sharing l16), add sink
  lsum += __shfl_xor(lsum, 16);
  lsum += __shfl_xor(lsum, 32);
  float sk = exp2f(sinks[h] * L2E);
  float inv = 1.0f / (lsum + sk);     // lane (l16,lg) holds inv for local row l16
  // acc rows are local row lg*4+r -> fetch inv from lane (lg*4+r)
#pragma unroll
  for (int r = 0; r < 4; ++r) {
    float rd = __shfl(inv, lg * 4 + r);
    int row = q0 + wq * 16 + lg * 4 + r;
#pragma unroll
    for (int dt = 0; dt < 4; ++dt)
      ao[(size_t)row * HIDDEN + h * 64 + dt * 16 + l16] = f2bf(acc[dt][r] * rd);
  }
}

// ---------------------------------------------------------------------------
// Launch. Workspace layout (~33 MB of d_ws):
//   [0,8M)    xb      bf16 x            [4096][1024]
//   [8,11M)   wqkvb   bf16 wq|wk|wv     [1536][1024]
//   [11,13M)  wob     bf16 wo           [1024][1024]
//   [13,21M)  qsc     bf16 q (scaled)   [4096][1024]
//   [21,23M)  kbf     bf16 k            [4][4096][64]
//   [23,25M)  vtb     bf16 v^T          [4][64][4096]
//   [25,33M)  aob     bf16 attn out     [4096][1024]
// ---------------------------------------------------------------------------
extern "C" void kernel_launch(void* const* d_in, const int* in_sizes, int n_in,
                              void* d_out, int out_size, void* d_ws, size_t ws_size,
                              hipStream_t stream) {
  const float* x     = (const float*)d_in[0];
  const float* cosb  = (const float*)d_in[1];
  const float* sinb  = (const float*)d_in[2];
  const float* wq    = (const float*)d_in[3];
  const float* wk    = (const float*)d_in[4];
  const float* wv    = (const float*)d_in[5];
  const float* wo    = (const float*)d_in[6];
  const float* qnw   = (const float*)d_in[7];
  const float* knw   = (const float*)d_in[8];
  const float* sinks = (const float*)d_in[9];
  float* out = (float*)d_out;

  char* ws = (char*)d_ws;
  uint16_t* xb    = (uint16_t*)(ws);
  uint16_t* wqkvb = (uint16_t*)(ws + (8ll  << 20));
  uint16_t* wob   = (uint16_t*)(ws + (11ll << 20));
  uint16_t* qsc   = (uint16_t*)(ws + (13ll << 20));
  uint16_t* kbf   = (uint16_t*)(ws + (21ll << 20));
  uint16_t* vtb   = (uint16_t*)(ws + (23ll << 20));
  uint16_t* aob   = (uint16_t*)(ws + (25ll << 20));

  k_tobf16  <<<6656, 256, 0, stream>>>(x, wq, wk, wv, wo, xb, wqkvb, wob);
  k_gemm_qkv<<<768, 256, 0, stream>>>(xb, wqkvb, cosb, sinb, qnw, knw,
                                      qsc, kbf, vtb);
  k_attn    <<<512, 512, 0, stream>>>(qsc, kbf, vtb, sinks, aob);
  k_gemm_bf16<<<512, 256, 0, stream>>>(aob, wob, out, 1024, 1024);
}